// Round 7
// baseline (32318.643 us; speedup 1.0000x reference)
//
#include <hip/hip_runtime.h>

// TinyRNNPolicy: h_{t+1} = tanh(W h_t); action_t = tanh(mean(h_{t+1}[:2048]))
//
// R7: persistent kernel, 256 blocks x 512 threads (1 block/CU, 8 waves).
// Barrier-free step exchange (R6 structure) with 32-BIT tagged words:
// each fp32 h value -> two words (tag16=step | 16 bits of fp32). All
// cross-block traffic is plain 32-bit agent-scope loads/stores -- R6 proved
// 64-bit agent "loads" compile to RMW atomics (WRITE_SIZE 115MB -> 44GB).
// Consumer poll = data load: one coherence hop, no flags/fences/vmcnt in
// the main loop. 2-buffer ping-pong race-free: producer reaching s+2 implies
// every block consumed h_{s+1}, hence every block consumed h_s.
// W slice (128 floats/thread) AGPR-pinned (R6: VGPR=128arch+128acc took).
// LDS staging keeps the measured-zero-conflict one-float4-per-thread mapping.

#define N 4096
#define HALF 2048
#define BLOCKS 256
#define TPB 512
#define RPB 16        // rows per block
#define CCOLS 128     // cols per thread-chunk
#define NCH 32        // chunks (4096/128)
#define PAD 132       // LDS chunk stride in floats (132%32==4)

// ws layout (dword offsets); ws re-poisoned 0xAA each launch -> init kernel.
// Poison tag 0xAAAA (43690) > max real tag 4097 -> never matches.
#define WS_FLAGS 0            // 256 flags, stride 16 dwords (post-loop barrier)
#define WS_HTA   4096         // tagged h ping: 4096 elems x 2 words
#define WS_HTB   12288        // tagged h pong
#define WS_ACC   20480        // accum[out_size] (fallback path only)
#define WS_PART  24576        // parts[n_steps*128] (big path)

typedef float f32x16 __attribute__((ext_vector_type(16)));

__device__ __forceinline__ float agent_ld(const float* p) {
    return __hip_atomic_load(p, __ATOMIC_RELAXED, __HIP_MEMORY_SCOPE_AGENT);
}
__device__ __forceinline__ void agent_st(float* p, float v) {
    __hip_atomic_store(p, v, __ATOMIC_RELAXED, __HIP_MEMORY_SCOPE_AGENT);
}
__device__ __forceinline__ unsigned agent_ldu(const unsigned* p) {
    return __hip_atomic_load(p, __ATOMIC_RELAXED, __HIP_MEMORY_SCOPE_AGENT);
}
__device__ __forceinline__ void agent_stu(unsigned* p, unsigned v) {
    __hip_atomic_store(p, v, __ATOMIC_RELAXED, __HIP_MEMORY_SCOPE_AGENT);
}

__device__ __forceinline__ float tanh_fast(float x) {
    x = fminf(fmaxf(x, -15.0f), 15.0f);   // clamp avoids inf/inf
    float e = __expf(2.0f * x);
    return (e - 1.0f) / (e + 1.0f);       // exact 0 at x==0
}

__global__ void rnn_init(const float* __restrict__ h0, float* __restrict__ ws, int n_out) {
    int i = blockIdx.x * blockDim.x + threadIdx.x;
    if (i < BLOCKS * 16) agent_stu((unsigned*)ws + WS_FLAGS + i, 0u);
    if (i < n_out) agent_st(ws + WS_ACC + i, 0.0f);
    if (i < N) {   // h_0 tagged 0 into buffer A
        unsigned bits = __float_as_uint(h0[i]);
        unsigned* hw = (unsigned*)ws + WS_HTA;
        agent_stu(hw + 2*i + 0, bits >> 16);        // tag 0 | hi16
        agent_stu(hw + 2*i + 1, bits & 0xffffu);    // tag 0 | lo16
    }
}

__global__ void __launch_bounds__(TPB, 2)
rnn_persistent(const float* __restrict__ W, const int* __restrict__ pns,
               float* __restrict__ out, float* __restrict__ ws, int big) {
    const int b = blockIdx.x;
    const int t = threadIdx.x;
    const int lane = t & 63;
    const int wave = t >> 6;       // 0..7
    const int row = t & 15;        // row within block's 16 rows
    const int chunk = t >> 4;      // 0..31, 128-col chunk
    const int grow = b * RPB + row;

    // ---- one-time: W slice (128 floats/thread) -> AGPR-class vectors ----
    f32x16 wa[8];
    {
        const float4* Wv = (const float4*)(W + (size_t)grow * N + (size_t)chunk * CCOLS);
#pragma unroll
        for (int i = 0; i < 8; ++i) {
#pragma unroll
            for (int q = 0; q < 4; ++q) {
                float4 v = Wv[i * 4 + q];
                wa[i][4*q+0] = v.x; wa[i][4*q+1] = v.y;
                wa[i][4*q+2] = v.z; wa[i][4*q+3] = v.w;
            }
        }
    }

    const int n_steps = *pns;

    __shared__ float hs[NCH * PAD];   // padded h broadcast (~16.5 KiB)
    __shared__ float part[128];       // 8 waves x 16 rows

    unsigned* flags = (unsigned*)ws + WS_FLAGS;
    unsigned* hWA  = (unsigned*)ws + WS_HTA;
    unsigned* hWB  = (unsigned*)ws + WS_HTB;
    float* accum = ws + WS_ACC;
    float* parts = ws + WS_PART;

    for (int s = 0; s < n_steps; ++s) {
        // pin W into AGPRs each iteration (home class AGPR, no competitors)
#pragma unroll
        for (int i = 0; i < 8; ++i) asm volatile("" : "+a"(wa[i]));

        const unsigned* src = (s & 1) ? hWB : hWA;
        unsigned*       dst = (s & 1) ? hWA : hWB;
        const unsigned etag = (unsigned)s;      // h_s words carry tag s

        // ---- poll+load this thread's 8 h elements = 16 tagged words.
        //      The poll IS the data load: one coherence hop per step. ----
        unsigned g[16];
        {
            const unsigned* p0 = src + 8 * t;            // elems 4t..4t+3
            const unsigned* p1 = src + 2 * 2048 + 8 * t; // elems 2048+4t..+3
            unsigned spins = 0;
            for (;;) {
                bool ok = true;
#pragma unroll
                for (int i = 0; i < 8; ++i) g[i] = agent_ldu(p0 + i);
#pragma unroll
                for (int i = 0; i < 8; ++i) g[8 + i] = agent_ldu(p1 + i);
#pragma unroll
                for (int i = 0; i < 16; ++i) ok &= ((g[i] >> 16) == etag);
                if (ok) break;
                __builtin_amdgcn_s_sleep(1);
                if (++spins > (1u << 20)) break;   // fail loud, don't hang
            }
        }

        // ---- reconstruct fp32 + stage to LDS (zero-conflict mapping) ----
        {
            float v0 = __uint_as_float((g[0] << 16) | (g[1] & 0xffffu));
            float v1 = __uint_as_float((g[2] << 16) | (g[3] & 0xffffu));
            float v2 = __uint_as_float((g[4] << 16) | (g[5] & 0xffffu));
            float v3 = __uint_as_float((g[6] << 16) | (g[7] & 0xffffu));
            int base0 = (t >> 5) * PAD + 4 * (t & 31);              // idx = t
            *(float4*)&hs[base0] = make_float4(v0, v1, v2, v3);
            float u0 = __uint_as_float((g[8]  << 16) | (g[9]  & 0xffffu));
            float u1 = __uint_as_float((g[10] << 16) | (g[11] & 0xffffu));
            float u2 = __uint_as_float((g[12] << 16) | (g[13] & 0xffffu));
            float u3 = __uint_as_float((g[14] << 16) | (g[15] & 0xffffu));
            int idx1 = t + TPB;                                     // idx = t+512
            int base1 = (idx1 >> 5) * PAD + 4 * (idx1 & 31);
            *(float4*)&hs[base1] = make_float4(u0, u1, u2, u3);
        }
        __syncthreads();

        // ---- 128 FMAs over this thread's chunk; W sourced from AGPRs ----
        float s0 = 0.f, s1 = 0.f, s2 = 0.f, s3 = 0.f;
        const int hb = chunk * PAD;
#pragma unroll
        for (int k = 0; k < CCOLS; k += 4) {
            float4 hv = *(const float4*)&hs[hb + k];
            s0 = fmaf(wa[k >> 4][(k & 15) + 0], hv.x, s0);
            s1 = fmaf(wa[k >> 4][(k & 15) + 1], hv.y, s1);
            s2 = fmaf(wa[k >> 4][(k & 15) + 2], hv.z, s2);
            s3 = fmaf(wa[k >> 4][(k & 15) + 3], hv.w, s3);
        }
        float v = (s0 + s1) + (s2 + s3);

        // ---- intra-wave reduce: wave's 4 chunks -> lanes 0..15 (16 rows) ----
        v += __shfl_down(v, 32);
        v += __shfl_down(v, 16);
        if (lane < 16) part[wave * 16 + lane] = v;
        __syncthreads();

        // ---- wave 0: final reduce, tanh, publish tagged h (data IS flag) ----
        if (wave == 0) {
            float hval = 0.0f;
            if (t < RPB) {
                float acc = 0.0f;
#pragma unroll
                for (int c = 0; c < TPB / 64; ++c) acc += part[c * 16 + t];
                hval = tanh_fast(acc);
                unsigned bits = __float_as_uint(hval);
                unsigned tag  = (unsigned)(s + 1) << 16;
                int gi = b * RPB + t;
                agent_stu(dst + 2*gi + 0, tag | (bits >> 16));
                agent_stu(dst + 2*gi + 1, tag | (bits & 0xffffu));
            }
            // readout partial: sum of this block's 16 h values
            float r = (t < RPB) ? hval : 0.0f;
            r += __shfl_down(r, 8);
            r += __shfl_down(r, 4);
            r += __shfl_down(r, 2);
            r += __shfl_down(r, 1);
            if (t == 0 && b < (BLOCKS / 2)) {
                if (big) agent_st(parts + (size_t)s * 128 + b, r);
                else     atomicAdd(accum + s, r);
            }
        }

        // ---- fallback (!big): per-step flag barrier to finalize out[s] ----
        if (!big) {
            __syncthreads();
            if (wave == 0) {
                asm volatile("s_waitcnt vmcnt(0)" ::: "memory");
                if (t == 0) agent_stu(flags + b * 16, (unsigned)(s + 1));
            }
            if (t < BLOCKS) {
                unsigned spins = 0;
                while (agent_ldu(flags + t * 16) < (unsigned)(s + 1)) {
                    __builtin_amdgcn_s_sleep(1);
                    if (++spins > (1u << 20)) break;
                }
            }
            __syncthreads();
            if (b == 0 && t == 0)
                out[s] = tanh_fast(agent_ld(accum + s) * (1.0f / (float)HALF));
        }
        // big path: NO per-step barrier; next iteration's poll enforces order.
    }

    // ---- big path: one final barrier, then all outputs in parallel ----
    if (big) {
        __syncthreads();
        if (wave == 0) {
            asm volatile("s_waitcnt vmcnt(0)" ::: "memory");
            if (t == 0) agent_stu(flags + b * 16, (unsigned)(n_steps + 1));
        }
        if (t < BLOCKS) {
            unsigned spins = 0;
            while (agent_ldu(flags + t * 16) < (unsigned)(n_steps + 1)) {
                __builtin_amdgcn_s_sleep(1);
                if (++spins > (1u << 20)) break;
            }
        }
        __syncthreads();

        const int l = t & 63;
        for (int ss = b * 8 + (t >> 6); ss < n_steps; ss += BLOCKS * 8) {
            float v = agent_ld(parts + (size_t)ss * 128 + l)
                    + agent_ld(parts + (size_t)ss * 128 + 64 + l);
            v += __shfl_down(v, 32);
            v += __shfl_down(v, 16);
            v += __shfl_down(v, 8);
            v += __shfl_down(v, 4);
            v += __shfl_down(v, 2);
            v += __shfl_down(v, 1);
            if (l == 0) out[ss] = tanh_fast(v * (1.0f / (float)HALF));
        }
    }
}

extern "C" void kernel_launch(void* const* d_in, const int* in_sizes, int n_in,
                              void* d_out, int out_size, void* d_ws, size_t ws_size,
                              hipStream_t stream) {
    const float* W  = (const float*)d_in[0];
    const float* h0 = (const float*)d_in[1];
    const int*  pns = (const int*)d_in[2];
    float* out = (float*)d_out;
    float* ws  = (float*)d_ws;

    size_t need = ((size_t)WS_PART + (size_t)out_size * 128) * 4;
    int big = (ws_size >= need) ? 1 : 0;

    int n_init = out_size > N ? out_size : N;
    rnn_init<<<(n_init + 255) / 256, 256, 0, stream>>>(h0, ws, out_size);
    rnn_persistent<<<BLOCKS, TPB, 0, stream>>>(W, pns, out, ws, big);
}